// Round 1
// baseline (189.806 us; speedup 1.0000x reference)
//
#include <hip/hip_runtime.h>

#define BATCH   512
#define IN_DIM  16384
#define KNN     32

// ---------------------------------------------------------------------------
// Transpose x (BATCH, IN_DIM) -> xt (IN_DIM, BATCH), 32x32 LDS tiles.
// ---------------------------------------------------------------------------
__global__ __launch_bounds__(256) void transpose_k(const float* __restrict__ in,
                                                   float* __restrict__ out) {
    __shared__ float tile[32][33];   // +1 pad: conflict-free column reads
    const int bx = blockIdx.x * 32;  // column base (IN_DIM axis)
    const int by = blockIdx.y * 32;  // row base (BATCH axis)
    const int tx = threadIdx.x;      // 0..31
    const int ty = threadIdx.y;      // 0..7
#pragma unroll
    for (int j = 0; j < 32; j += 8)
        tile[ty + j][tx] = in[(size_t)(by + ty + j) * IN_DIM + bx + tx];
    __syncthreads();
#pragma unroll
    for (int j = 0; j < 32; j += 8)
        out[(size_t)(bx + ty + j) * BATCH + by + tx] = tile[tx][ty + j];
}

// ---------------------------------------------------------------------------
// One locally-connected layer, transposed layout.
//   yt[d, b] = relu( sum_k w[d,k] * xt[knn[d,k], b] + bias[d] )
// One block per output feature d; 128 threads x float4 covers all 512 batch.
// knn/w/bias reads are wave-uniform (scalar); gather rows are coalesced.
// ---------------------------------------------------------------------------
__global__ __launch_bounds__(128) void lcn_layer_k(const float* __restrict__ xt,
                                                   const float* __restrict__ w,
                                                   const float* __restrict__ bias,
                                                   const int* __restrict__ knn,
                                                   float* __restrict__ yt) {
    const int d  = blockIdx.x;
    const int b4 = threadIdx.x;          // handles batch 4*b4 .. 4*b4+3
    const int*   kp = knn + d * KNN;
    const float* wp = w   + d * KNN;

    float4 acc = make_float4(0.f, 0.f, 0.f, 0.f);
#pragma unroll
    for (int k = 0; k < KNN; ++k) {
        const int   idx = kp[k];         // uniform
        const float wv  = wp[k];         // uniform
        const float4 v  = *(const float4*)(xt + (size_t)idx * BATCH + 4 * b4);
        acc.x += wv * v.x;
        acc.y += wv * v.y;
        acc.z += wv * v.z;
        acc.w += wv * v.w;
    }
    const float bv = bias[d];
    acc.x = fmaxf(acc.x + bv, 0.f);
    acc.y = fmaxf(acc.y + bv, 0.f);
    acc.z = fmaxf(acc.z + bv, 0.f);
    acc.w = fmaxf(acc.w + bv, 0.f);
    *(float4*)(yt + (size_t)d * BATCH + 4 * b4) = acc;
}

// ---------------------------------------------------------------------------
// Final FC: out[b, o] = sum_d y2t[d, b] * fcw[d, o] + fcb[o]
// One thread per output element (512*16 = 8192 threads), 4-way split
// accumulators to break the dependent-FMA chain.
// ---------------------------------------------------------------------------
__global__ __launch_bounds__(256) void fc_k(const float* __restrict__ y2t,
                                            const float* __restrict__ fcw,
                                            const float* __restrict__ fcb,
                                            float* __restrict__ out) {
    const int t = blockIdx.x * 256 + threadIdx.x;  // 0..8191
    const int o = t & 15;
    const int b = t >> 4;
    float a0 = 0.f, a1 = 0.f, a2 = 0.f, a3 = 0.f;
#pragma unroll 4
    for (int d = 0; d < 2048; d += 4) {
        a0 += y2t[(size_t)(d + 0) * BATCH + b] * fcw[(d + 0) * 16 + o];
        a1 += y2t[(size_t)(d + 1) * BATCH + b] * fcw[(d + 1) * 16 + o];
        a2 += y2t[(size_t)(d + 2) * BATCH + b] * fcw[(d + 2) * 16 + o];
        a3 += y2t[(size_t)(d + 3) * BATCH + b] * fcw[(d + 3) * 16 + o];
    }
    out[t] = (a0 + a1) + (a2 + a3) + fcb[o];
}

extern "C" void kernel_launch(void* const* d_in, const int* in_sizes, int n_in,
                              void* d_out, int out_size, void* d_ws, size_t ws_size,
                              hipStream_t stream) {
    // setup_inputs() dict order:
    // x, w0, b0, knn0, w1, b1, knn1, w2, b2, knn2, fc_w, fc_b
    const float* x    = (const float*)d_in[0];
    const float* w0   = (const float*)d_in[1];
    const float* b0   = (const float*)d_in[2];
    const int*   knn0 = (const int*)  d_in[3];
    const float* w1   = (const float*)d_in[4];
    const float* b1   = (const float*)d_in[5];
    const int*   knn1 = (const int*)  d_in[6];
    const float* w2   = (const float*)d_in[7];
    const float* b2   = (const float*)d_in[8];
    const int*   knn2 = (const int*)  d_in[9];
    const float* fcw  = (const float*)d_in[10];
    const float* fcb  = (const float*)d_in[11];
    float* out = (float*)d_out;

    // Workspace layout (48 MB peak):
    //   xt  @ 0      : 16384*512*4 = 32 MB   (live through layer 0)
    //   y0t @ 32 MB  :  8192*512*4 = 16 MB   (live through layer 1)
    //   y1t @ 0      :  4096*512*4 =  8 MB   (reuses xt region)
    //   y2t @ 8 MB   :  2048*512*4 =  4 MB   (after y1t, inside old xt region)
    char* ws = (char*)d_ws;
    float* xt  = (float*)(ws);
    float* y0t = (float*)(ws + (size_t)(32u << 20));
    float* y1t = (float*)(ws);
    float* y2t = (float*)(ws + (size_t)(8u << 20));

    transpose_k<<<dim3(IN_DIM / 32, BATCH / 32), dim3(32, 8), 0, stream>>>(x, xt);
    lcn_layer_k<<<8192, 128, 0, stream>>>(xt,  w0, b0, knn0, y0t);
    lcn_layer_k<<<4096, 128, 0, stream>>>(y0t, w1, b1, knn1, y1t);
    lcn_layer_k<<<2048, 128, 0, stream>>>(y1t, w2, b2, knn2, y2t);
    fc_k<<<32, 256, 0, stream>>>(y2t, fcw, fcb, out);
}

// Round 2
// 70.324 us; speedup vs baseline: 2.6990x; 2.6990x over previous
//
#include <hip/hip_runtime.h>
#include <hip/hip_fp16.h>

#define BATCH   512
#define IN_DIM  16384
#define KNN     32
#define NCHUNK  8          // 8 batch chunks of 64 -> pinned to 8 XCDs via bid&7
#define CHUNK   64

typedef __attribute__((ext_vector_type(4))) _Float16 half4v;

// ---------------------------------------------------------------------------
// Transpose x (BATCH, IN_DIM) fp32 -> xt (IN_DIM, BATCH) fp16.
// 32x32 tile in LDS; store phase packs 4 halves (8B) per thread.
// ---------------------------------------------------------------------------
__global__ __launch_bounds__(256) void transpose_h(const float* __restrict__ in,
                                                   _Float16* __restrict__ out) {
    __shared__ float tile[32][33];
    const int bx = blockIdx.x * 32;          // IN_DIM base
    const int by = blockIdx.y * 32;          // BATCH base
    const int tx = threadIdx.x & 31;
    const int ty = threadIdx.x >> 5;         // 0..7
#pragma unroll
    for (int j = 0; j < 32; j += 8)
        tile[ty + j][tx] = in[(size_t)(by + ty + j) * IN_DIM + bx + tx];
    __syncthreads();
    const int r = threadIdx.x >> 3;          // 0..31  (local d)
    const int c = (threadIdx.x & 7) * 4;     // local batch base
    half4v h;
    h[0] = (_Float16)tile[c + 0][r];
    h[1] = (_Float16)tile[c + 1][r];
    h[2] = (_Float16)tile[c + 2][r];
    h[3] = (_Float16)tile[c + 3][r];
    *(half4v*)(out + (size_t)(bx + r) * BATCH + by + c) = h;
}

// ---------------------------------------------------------------------------
// One locally-connected layer, fp16 transposed layout, XCD-pinned chunks.
//   yt[d, b] = relu( sum_k w[d,k] * xt[knn[d,k], b] + bias[d] )
// Block = 1 wave = 64 lanes = one 64-wide batch chunk of one output feature.
// chunk = blockIdx.x & 7: consecutive blocks round-robin across the 8 XCDs,
// so each XCD's L2 holds only its own 1/8 column-slab of xt (<= 2 MB).
// Gather per (d,k) = one 128B cache line per wave.
// knn/w/bias reads are block-uniform -> scalar loads.
// ---------------------------------------------------------------------------
__global__ __launch_bounds__(64) void lcn_layer_h(const _Float16* __restrict__ xt,
                                                  const float* __restrict__ w,
                                                  const float* __restrict__ bias,
                                                  const int* __restrict__ knn,
                                                  _Float16* __restrict__ yt) {
    const int d  = blockIdx.x >> 3;
    const int b  = (blockIdx.x & 7) * CHUNK + threadIdx.x;
    const int*   kp = knn + d * KNN;
    const float* wp = w   + d * KNN;
    float acc = 0.f;
#pragma unroll
    for (int k = 0; k < KNN; ++k) {
        const int   idx = kp[k];                               // scalar
        const float wv  = wp[k];                               // scalar
        acc += wv * (float)xt[(size_t)idx * BATCH + b];        // 128B/wave, L2-hit
    }
    acc = fmaxf(acc + bias[d], 0.f);
    yt[(size_t)d * BATCH + b] = (_Float16)acc;
}

// ---------------------------------------------------------------------------
// FC stage 1: partial sums over d-chunks of 256.
//   part[(b*16+o)*8 + ch] = sum_{d in ch} y2t[d,b] * fcw[d,o]
// Grid 256 blocks: o = bx&15, b-half = (bx>>4)&1, ch = bx>>5.
// y2t loads coalesced (b in lane); fcw loads block-uniform scalars.
// ---------------------------------------------------------------------------
__global__ __launch_bounds__(256) void fc_partial(const _Float16* __restrict__ y2t,
                                                  const float* __restrict__ fcw,
                                                  float* __restrict__ part) {
    const int o  = blockIdx.x & 15;
    const int bh = (blockIdx.x >> 4) & 1;
    const int ch = blockIdx.x >> 5;          // 0..7
    const int b  = bh * 256 + threadIdx.x;
    const int d0 = ch * 256;
    float a0 = 0.f, a1 = 0.f, a2 = 0.f, a3 = 0.f;
#pragma unroll 4
    for (int d = d0; d < d0 + 256; d += 4) {
        a0 += (float)y2t[(size_t)(d + 0) * BATCH + b] * fcw[(d + 0) * 16 + o];
        a1 += (float)y2t[(size_t)(d + 1) * BATCH + b] * fcw[(d + 1) * 16 + o];
        a2 += (float)y2t[(size_t)(d + 2) * BATCH + b] * fcw[(d + 2) * 16 + o];
        a3 += (float)y2t[(size_t)(d + 3) * BATCH + b] * fcw[(d + 3) * 16 + o];
    }
    part[((size_t)b * 16 + o) * 8 + ch] = (a0 + a1) + (a2 + a3);
}

// FC stage 2: reduce the 8 partials + bias. out[b*16+o], 8192 threads.
__global__ __launch_bounds__(256) void fc_final(const float* __restrict__ part,
                                                const float* __restrict__ fcb,
                                                float* __restrict__ out) {
    const int t = blockIdx.x * 256 + threadIdx.x;       // 0..8191
    const float4 p0 = *(const float4*)(part + (size_t)t * 8);
    const float4 p1 = *(const float4*)(part + (size_t)t * 8 + 4);
    out[t] = ((p0.x + p0.y) + (p0.z + p0.w)) + ((p1.x + p1.y) + (p1.z + p1.w))
             + fcb[t & 15];
}

extern "C" void kernel_launch(void* const* d_in, const int* in_sizes, int n_in,
                              void* d_out, int out_size, void* d_ws, size_t ws_size,
                              hipStream_t stream) {
    // setup_inputs() order: x, w0,b0,knn0, w1,b1,knn1, w2,b2,knn2, fc_w, fc_b
    const float* x    = (const float*)d_in[0];
    const float* w0   = (const float*)d_in[1];
    const float* b0   = (const float*)d_in[2];
    const int*   knn0 = (const int*)  d_in[3];
    const float* w1   = (const float*)d_in[4];
    const float* b1   = (const float*)d_in[5];
    const int*   knn1 = (const int*)  d_in[6];
    const float* w2   = (const float*)d_in[7];
    const float* b2   = (const float*)d_in[8];
    const int*   knn2 = (const int*)  d_in[9];
    const float* fcw  = (const float*)d_in[10];
    const float* fcb  = (const float*)d_in[11];
    float* out = (float*)d_out;

    // Workspace (fp16 intermediates, non-overlapping, 30.25 MB total):
    //   xt   @  0 MB : 16384*512*2 = 16 MB
    //   y0t  @ 16 MB :  8192*512*2 =  8 MB
    //   y1t  @ 24 MB :  4096*512*2 =  4 MB
    //   y2t  @ 28 MB :  2048*512*2 =  2 MB
    //   part @ 30 MB :  8192*8*4   = 256 KB
    char* ws = (char*)d_ws;
    _Float16* xt   = (_Float16*)(ws);
    _Float16* y0t  = (_Float16*)(ws + ((size_t)16 << 20));
    _Float16* y1t  = (_Float16*)(ws + ((size_t)24 << 20));
    _Float16* y2t  = (_Float16*)(ws + ((size_t)28 << 20));
    float*    part = (float*)   (ws + ((size_t)30 << 20));

    transpose_h<<<dim3(IN_DIM / 32, BATCH / 32), 256, 0, stream>>>(x, xt);
    lcn_layer_h<<<8192 * NCHUNK, 64, 0, stream>>>(xt,  w0, b0, knn0, y0t);
    lcn_layer_h<<<4096 * NCHUNK, 64, 0, stream>>>(y0t, w1, b1, knn1, y1t);
    lcn_layer_h<<<2048 * NCHUNK, 64, 0, stream>>>(y1t, w2, b2, knn2, y2t);
    fc_partial<<<256, 256, 0, stream>>>(y2t, fcw, part);
    fc_final<<<32, 256, 0, stream>>>(part, fcb, out);
}